// Round 16
// baseline (536.014 us; speedup 1.0000x reference)
//
#include <hip/hip_runtime.h>
#include <math.h>

// Problem constants (match reference setup_inputs)
constexpr int NN  = 50000;   // nodes
constexpr int NE  = 640000;  // edges
constexpr int DIN = 256;
constexpr int DE  = 64;
constexpr int H1  = 128;
constexpr int H2  = 64;

using u16 = unsigned short;
typedef __attribute__((ext_vector_type(8))) short bf16x8;
typedef __attribute__((ext_vector_type(4))) float f32x4;

// ---- fp32 -> bf16 (RTN) and back ----
__device__ inline u16 f2bf(float f) {
  unsigned u = __float_as_uint(f);
  unsigned r = (u + 0x7FFFu + ((u >> 16) & 1u)) >> 16;
  return (u16)r;
}
__device__ inline float bf2f(u16 h) { return __uint_as_float(((unsigned)h) << 16); }
__device__ inline unsigned pack2(u16 a, u16 b) {
  return (unsigned)a | ((unsigned)b << 16);
}
__device__ inline f32x4 mfma16(bf16x8 a, bf16x8 b, f32x4 c) {
  return __builtin_amdgcn_mfma_f32_16x16x32_bf16(a, b, c, 0, 0, 0);
}

// ---- pack nmats weight matrices W[K,C] into transposed split Bt[n][k] (n = which*C+cc)
__global__ __launch_bounds__(256) void packwt_kernel(
    const float* __restrict__ W0, const float* __restrict__ W1,
    const float* __restrict__ W2, const float* __restrict__ W3,
    const float* __restrict__ b0, const float* __restrict__ b1,
    const float* __restrict__ b2, const float* __restrict__ b3,
    u16* __restrict__ Bth, u16* __restrict__ Btl, float* __restrict__ bcat,
    int K, int C, int nmats) {
  int total = nmats * C * K;
  for (int idx = blockIdx.x * blockDim.x + threadIdx.x; idx < total;
       idx += gridDim.x * blockDim.x) {
    int k = idx % K;
    int n = idx / K;             // n = which*C + cc
    int which = n / C, cc = n % C;
    const float* W = which == 0 ? W0 : which == 1 ? W1 : which == 2 ? W2 : W3;
    float v = W[k * C + cc];
    u16 h = f2bf(v);
    Bth[(size_t)n * K + k] = h;
    if (Btl) Btl[(size_t)n * K + k] = f2bf(v - bf2f(h));
    if (k == 0 && bcat) {
      const float* b = which == 0 ? b0 : which == 1 ? b1 : which == 2 ? b2 : b3;
      bcat[n] = b ? b[cc] : 0.f;
    }
  }
}

// ---- straight elementwise split copy: W (f32) -> hi/lo bf16, same layout ----
__global__ __launch_bounds__(256) void splitcopy_kernel(
    const float* __restrict__ W, u16* __restrict__ Bh, u16* __restrict__ Bl,
    int count) {
  int i = blockIdx.x * blockDim.x + threadIdx.x;
  if (i < count) {
    float v = W[i];
    u16 h = f2bf(v);
    Bh[i] = h;
    Bl[i] = f2bf(v - bf2f(h));
  }
}

// ---- CSR build ----
__global__ __launch_bounds__(256) void hist_kernel(const int* __restrict__ dst,
                                                   int* __restrict__ deg, int nE) {
  int e = blockIdx.x * blockDim.x + threadIdx.x;
  if (e < nE) atomicAdd(&deg[dst[e]], 1);
}

__global__ __launch_bounds__(256) void scan1_kernel(const int* __restrict__ deg,
                                                    int* __restrict__ part,
                                                    int* __restrict__ chunkSums,
                                                    int n) {
  __shared__ int s[256];
  int tid = threadIdx.x;
  int i = blockIdx.x * 256 + tid;
  int v0 = (i < n) ? deg[i] : 0;
  s[tid] = v0;
  __syncthreads();
  for (int off = 1; off < 256; off <<= 1) {
    int v = (tid >= off) ? s[tid - off] : 0;
    __syncthreads();
    s[tid] += v;
    __syncthreads();
  }
  if (i < n) part[i] = s[tid];
  if (tid == 255) chunkSums[blockIdx.x] = s[255];
}

__global__ __launch_bounds__(256) void scan2_kernel(int* __restrict__ chunkSums,
                                                    int nchunks) {
  __shared__ int s[256];
  int tid = threadIdx.x;
  s[tid] = (tid < nchunks) ? chunkSums[tid] : 0;
  __syncthreads();
  for (int off = 1; off < 256; off <<= 1) {
    int v = (tid >= off) ? s[tid - off] : 0;
    __syncthreads();
    s[tid] += v;
    __syncthreads();
  }
  if (tid < nchunks) chunkSums[tid] = s[tid];
}

__global__ __launch_bounds__(256) void scan3_kernel(const int* __restrict__ deg,
                                                    const int* __restrict__ part,
                                                    const int* __restrict__ chunkSums,
                                                    int* __restrict__ row_start,
                                                    int n, int nE) {
  int i = blockIdx.x * 256 + threadIdx.x;
  if (i < n)
    row_start[i] = part[i] - deg[i] + (blockIdx.x ? chunkSums[blockIdx.x - 1] : 0);
  if (i == 0) row_start[n] = nE;
}

__global__ __launch_bounds__(256) void scatter_kernel(const int* __restrict__ dst,
                                                      const int* __restrict__ row_start,
                                                      int* __restrict__ cursor,
                                                      int* __restrict__ eid, int nE) {
  int e = blockIdx.x * blockDim.x + threadIdx.x;
  if (e >= nE) return;
  int d = dst[e];
  int pos = row_start[d] + atomicAdd(&cursor[d], 1);
  eid[pos] = e;
}

__global__ __launch_bounds__(256) void sort_extract_kernel(
    int* __restrict__ eid, const int* __restrict__ row_start,
    const int* __restrict__ srcI, int* __restrict__ src_csr, int n) {
  int v = blockIdx.x * blockDim.x + threadIdx.x;
  if (v >= n) return;
  int b = row_start[v], e = row_start[v + 1];
  for (int i = b + 1; i < e; i++) {
    int key = eid[i];
    int j = i - 1;
    while (j >= b && eid[j] > key) { eid[j + 1] = eid[j]; j--; }
    eid[j + 1] = key;
  }
  for (int i = b; i < e; i++) src_csr[i] = srcI[eid[i]];
}

// ---- gather edge_attr into CSR order as bf16: EAc[i][d] = bf16(EAttr[eid[i]][d])
// 32 lanes per edge, 2 channels per lane (random 256B row read, sequential write).
__global__ __launch_bounds__(256) void ea_gather_kernel(
    const float* __restrict__ EAttr, const int* __restrict__ eid,
    u16* __restrict__ EAc, int nE) {
  int i = blockIdx.x * 8 + (threadIdx.x >> 5);
  int l = threadIdx.x & 31;
  if (i >= nE) return;
  int eo = eid[i];
  float2 v = *(const float2*)(EAttr + (size_t)eo * DE + l * 2);
  *(unsigned*)(EAc + (size_t)i * DE + l * 2) = pack2(f2bf(v.x), f2bf(v.y));
}

// ---- split-bf16 MFMA GEMM (generic, BM=128, 256 thr):
// out[M,Nn] = A[M,K](f32) @ Bt^T + bias
// EPI=0: fp32 -> Cout (stride Nn)
// EPI=2: projection split: cols [0,Cl)->Qp f32, [Cl,3Cl)->KVp bf16 [M][2Cl], [3Cl,4Cl)->Sp f32
// EPI=3: fp32 -> Cout with +Cin and relu: Cout = relu(acc + Cin)
template <int BN, int EPI>
__global__ __launch_bounds__(256) void mfma_gemm_kernel(
    const float* __restrict__ A, const int* __restrict__ ridx,
    const u16* __restrict__ Bth, const u16* __restrict__ Btl,
    const float* __restrict__ bias, float* __restrict__ Cout,
    float* __restrict__ Qp, u16* __restrict__ KVp, float* __restrict__ Sp,
    const float* __restrict__ Cin, int M, int Nn, int K, int Cl) {
  constexpr int BM = 128, BK = 32;
  constexpr int NI = BN / 32;  // 16-col frags per wave (wave covers BN/2)
  constexpr int SM_STAGE = (BM + BN) * BK * 2;
  constexpr int SM_EPI = (EPI == 2) ? BM * BN : 0;
  constexpr int SM = SM_STAGE > SM_EPI ? SM_STAGE : SM_EPI;
  __shared__ __align__(16) u16 smem[SM];
  u16* Ah = smem;
  u16* Al = smem + BM * BK;
  u16* Bh = smem + 2 * BM * BK;
  u16* Bl = smem + 2 * BM * BK + BN * BK;
  int tid = threadIdx.x;
  int lane = tid & 63, wid = tid >> 6;
  int wm = wid >> 1, wn = wid & 1;
  int row0 = blockIdx.y * BM, col0 = blockIdx.x * BN;
  int k8 = lane >> 4, rb = lane & 15;

  f32x4 acc[4][NI];
#pragma unroll
  for (int mi = 0; mi < 4; mi++)
#pragma unroll
    for (int ni = 0; ni < NI; ni++) acc[mi][ni] = (f32x4){0.f, 0.f, 0.f, 0.f};

  // A staging assignments: 2 chunks (8 f32 each) per thread
  size_t aoff[2];
  int sdst[2];
  for (int p = 0; p < 2; p++) {
    int idx = p * 256 + tid;
    int r = idx >> 2, c = idx & 3;
    int ar = row0 + r;
    if (ar >= M) ar = M - 1;
    if (ridx) ar = ridx[ar];
    aoff[p] = (size_t)ar * K + c * 8;
    sdst[p] = r * BK + ((c ^ ((r >> 1) & 3)) << 3);  // chunk-XOR swizzle
  }

  for (int k0 = 0; k0 < K; k0 += BK) {
    __syncthreads();
    // stage A: read f32, split to bf16 hi/lo
#pragma unroll
    for (int p = 0; p < 2; p++) {
      const float* s = A + aoff[p] + k0;
      float4 u = *(const float4*)s, v = *(const float4*)(s + 4);
      float f[8] = {u.x, u.y, u.z, u.w, v.x, v.y, v.z, v.w};
      u16 h[8], l[8];
#pragma unroll
      for (int j = 0; j < 8; j++) {
        h[j] = f2bf(f[j]);
        l[j] = f2bf(f[j] - bf2f(h[j]));
      }
      *(uint4*)&Ah[sdst[p]] = make_uint4(pack2(h[0], h[1]), pack2(h[2], h[3]),
                                         pack2(h[4], h[5]), pack2(h[6], h[7]));
      *(uint4*)&Al[sdst[p]] = make_uint4(pack2(l[0], l[1]), pack2(l[2], l[3]),
                                         pack2(l[4], l[5]), pack2(l[6], l[7]));
    }
    // stage B (already bf16 split, [Nn][K] row-major)
#pragma unroll
    for (int p = 0; p < (BN * 4 + 255) / 256; p++) {
      int idx = p * 256 + tid;
      if (idx < BN * 4) {
        int n = idx >> 2, c = idx & 3;
        size_t goff = (size_t)(col0 + n) * K + k0 + c * 8;
        int doff = n * BK + ((c ^ ((n >> 1) & 3)) << 3);
        *(uint4*)&Bh[doff] = *(const uint4*)&Bth[goff];
        *(uint4*)&Bl[doff] = *(const uint4*)&Btl[goff];
      }
    }
    __syncthreads();
    // fragments
    bf16x8 ah[4], al[4], bh[NI], bl[NI];
#pragma unroll
    for (int mi = 0; mi < 4; mi++) {
      int row = wm * 64 + mi * 16 + rb;
      int off = row * BK + ((k8 ^ ((row >> 1) & 3)) << 3);
      ah[mi] = *(const bf16x8*)&Ah[off];
      al[mi] = *(const bf16x8*)&Al[off];
    }
#pragma unroll
    for (int ni = 0; ni < NI; ni++) {
      int cn = wn * (BN / 2) + ni * 16 + rb;
      int off = cn * BK + ((k8 ^ ((cn >> 1) & 3)) << 3);
      bh[ni] = *(const bf16x8*)&Bh[off];
      bl[ni] = *(const bf16x8*)&Bl[off];
    }
#pragma unroll
    for (int mi = 0; mi < 4; mi++)
#pragma unroll
      for (int ni = 0; ni < NI; ni++) {
        f32x4 c = acc[mi][ni];
        c = mfma16(ah[mi], bh[ni], c);
        c = mfma16(al[mi], bh[ni], c);
        c = mfma16(ah[mi], bl[ni], c);
        acc[mi][ni] = c;
      }
  }

  // epilogue: D layout col=lane&15, row=(lane>>4)*4+reg (m89-verified)
  bool kvseg = false;
  if constexpr (EPI == 2) {
    int seg = col0 / Cl;
    kvseg = (seg == 1 || seg == 2);
    if (!kvseg) {
      float* dst = (seg == 0) ? Qp : Sp;
      int cbase = (seg == 0) ? col0 : col0 - 3 * Cl;
#pragma unroll
      for (int ni = 0; ni < NI; ni++) {
        int cfrag = wn * (BN / 2) + ni * 16 + rb;
        float bv = bias ? bias[col0 + cfrag] : 0.f;
#pragma unroll
        for (int mi = 0; mi < 4; mi++) {
#pragma unroll
          for (int q = 0; q < 4; q++) {
            int row = row0 + wm * 64 + mi * 16 + k8 * 4 + q;
            if (row < M)
              dst[(size_t)row * Cl + cbase + cfrag] = acc[mi][ni][q] + bv;
          }
        }
      }
      return;
    }
  }
  if (kvseg) {
    // stage bf16 tile in LDS (XOR-swizzled), then coalesced dwordx4 writes
    __syncthreads();
    u16* S = smem;  // [BM][BN] u16
#pragma unroll
    for (int ni = 0; ni < NI; ni++) {
      int coll = wn * (BN / 2) + ni * 16 + rb;
      float bv = bias ? bias[col0 + coll] : 0.f;
#pragma unroll
      for (int mi = 0; mi < 4; mi++) {
#pragma unroll
        for (int q = 0; q < 4; q++) {
          int rowl = wm * 64 + mi * 16 + k8 * 4 + q;
          S[rowl * BN + (coll ^ (((rowl >> 2) & 3) << 4))] =
              f2bf(acc[mi][ni][q] + bv);
        }
      }
    }
    __syncthreads();
    u16* dbase = KVp;
    size_t dstride = 2 * Cl;
    int dcol0 = col0 - Cl;
    constexpr int PASSES = (BM * BN * 2) / (256 * 16);
#pragma unroll
    for (int p = 0; p < PASSES; p++) {
      int idx = p * 256 + tid;      // uint4 index
      int r = idx / (BN / 8);
      int cp = idx % (BN / 8);
      int row = row0 + r;
      int cps = cp ^ (((r >> 2) & 3) << 1);  // inverse of the <<4 u16 swizzle
      if (row < M)
        *(uint4*)&dbase[(size_t)row * dstride + dcol0 + cp * 8] =
            *(const uint4*)&S[r * BN + cps * 8];
    }
    return;
  }
  if constexpr (EPI == 0 || EPI == 3) {
#pragma unroll
    for (int ni = 0; ni < NI; ni++) {
      int col = col0 + wn * (BN / 2) + ni * 16 + rb;
      float bv = (EPI == 0 && bias) ? bias[col] : 0.f;
#pragma unroll
      for (int mi = 0; mi < 4; mi++) {
#pragma unroll
        for (int q = 0; q < 4; q++) {
          int row = row0 + wm * 64 + mi * 16 + k8 * 4 + q;
          if (row < M) {
            if constexpr (EPI == 3) {
              float hv = acc[mi][ni][q] + Cin[(size_t)row * Nn + col];
              Cout[(size_t)row * Nn + col] = fmaxf(hv, 0.f);
            } else {
              Cout[(size_t)row * Nn + col] = acc[mi][ni][q] + bv;
            }
          }
        }
      }
    }
  }
}

// ---- fused edge pass (Ew-free): 8-edge-batched online softmax.
// logit = (q.k[src] + qe.ea) * scale, qe = We @ q precomputed; ea read from
// EAc (bf16, CSR order, sequential). Accumulates msg_v and msg_ea (64-dim).
// Writes Hp = msg_v*inv + skip (NO relu), EA = msg_ea*inv; post-GEMM
// h = relu(Hp + EA @ We) finishes the layer.
template <int C>
__global__ __launch_bounds__(256) void fused_edge_kernel(
    const float* __restrict__ Q, const float* __restrict__ QE,
    const float* __restrict__ SKIP, const u16* __restrict__ KV,
    const u16* __restrict__ EAc, const int* __restrict__ row_start,
    const int* __restrict__ src_csr, float* __restrict__ Hp,
    float* __restrict__ EA, float scale, int n) {
  constexpr int CPL = C / 64;  // channels per lane
  constexpr int EB = 8;        // edges per batch
  int node = blockIdx.x * 4 + (threadIdx.x >> 6);
  int lane = threadIdx.x & 63;
  if (node >= n) return;
  int ch = lane * CPL;
  float q[CPL], accv[CPL], skip[CPL];
#pragma unroll
  for (int j = 0; j < CPL; j++) {
    q[j] = Q[(size_t)node * C + ch + j];
    skip[j] = SKIP[(size_t)node * C + ch + j];
    accv[j] = 0.f;
  }
  float qe = QE[(size_t)node * DE + lane];
  float acc_ea = 0.f;
  float m = -INFINITY, denom = 0.f;
  int b = row_start[node], e = row_start[node + 1];
  for (int i = b; i < e; i += EB) {
    float part[EB], vv[EB][CPL], eaf[EB];
#pragma unroll
    for (int u = 0; u < EB; u++) {
      int idx = (i + u < e) ? i + u : e - 1;  // tail: clamp loads, zeroed by w=0
      int s = src_csr[idx];
      const u16* kvp = KV + (size_t)s * (2 * C);
      eaf[u] = bf2f(EAc[(size_t)idx * DE + lane]);
      float kk[CPL];
      if constexpr (CPL == 2) {
        unsigned uk = *(const unsigned*)(kvp + ch);
        unsigned uv = *(const unsigned*)(kvp + C + ch);
        kk[0] = bf2f((u16)uk); kk[1] = bf2f((u16)(uk >> 16));
        vv[u][0] = bf2f((u16)uv); vv[u][1] = bf2f((u16)(uv >> 16));
      } else {
        kk[0] = bf2f(kvp[ch]);
        vv[u][0] = bf2f(kvp[C + ch]);
      }
      float p = qe * eaf[u];
#pragma unroll
      for (int j = 0; j < CPL; j++) p = fmaf(q[j], kk[j], p);
      part[u] = p;
    }
    // EB independent butterfly reductions (ILP across trees)
#pragma unroll
    for (int off = 32; off > 0; off >>= 1) {
#pragma unroll
      for (int u = 0; u < EB; u++) part[u] += __shfl_xor(part[u], off);
    }
    float l[EB];
#pragma unroll
    for (int u = 0; u < EB; u++)
      l[u] = (i + u < e) ? part[u] * scale : -INFINITY;
    float bm = l[0];
#pragma unroll
    for (int u = 1; u < EB; u++) bm = fmaxf(bm, l[u]);
    float nm = fmaxf(bm, m);
    float f = expf(m - nm);  // 0 on first batch (m = -inf)
    float w[EB];
#pragma unroll
    for (int u = 0; u < EB; u++) w[u] = expf(l[u] - nm);  // -inf -> 0
    float wsum = 0.f;
#pragma unroll
    for (int u = 0; u < EB; u++) wsum += w[u];
    denom = denom * f + wsum;
#pragma unroll
    for (int j = 0; j < CPL; j++) {
      float a = accv[j] * f;
#pragma unroll
      for (int u = 0; u < EB; u++) a = fmaf(w[u], vv[u][j], a);
      accv[j] = a;
    }
    float ae = acc_ea * f;
#pragma unroll
    for (int u = 0; u < EB; u++) ae = fmaf(w[u], eaf[u], ae);
    acc_ea = ae;
    m = nm;
  }
  float inv = 1.f / (denom + 1e-16f);
#pragma unroll
  for (int j = 0; j < CPL; j++)
    Hp[(size_t)node * C + ch + j] = accv[j] * inv + skip[j];
  EA[(size_t)node * DE + lane] = acc_ea * inv;
}

// ---- out[n] = h2[n] @ Wc + bc  (wave per node) ----
__global__ __launch_bounds__(256) void classifier_kernel(
    const float* __restrict__ h2, const float* __restrict__ Wc,
    const float* __restrict__ bc, float* __restrict__ out, int n) {
  int w = blockIdx.x * 4 + (threadIdx.x >> 6);
  int lane = threadIdx.x & 63;
  if (w >= n) return;
  float v = h2[(size_t)w * 64 + lane] * Wc[lane];
#pragma unroll
  for (int off = 32; off > 0; off >>= 1) v += __shfl_xor(v, off);
  if (lane == 0) out[w] = v + bc[0];
}

extern "C" void kernel_launch(void* const* d_in, const int* in_sizes, int n_in,
                              void* d_out, int out_size, void* d_ws,
                              size_t ws_size, hipStream_t stream) {
  const float* x         = (const float*)d_in[0];
  const int*   ei        = (const int*)d_in[1];
  const float* edge_attr = (const float*)d_in[2];
  const float* Wq1 = (const float*)d_in[3];  const float* bq1 = (const float*)d_in[4];
  const float* Wk1 = (const float*)d_in[5];  const float* bk1 = (const float*)d_in[6];
  const float* Wv1 = (const float*)d_in[7];  const float* bv1 = (const float*)d_in[8];
  const float* We1 = (const float*)d_in[9];
  const float* Ws1 = (const float*)d_in[10]; const float* bs1 = (const float*)d_in[11];
  const float* Wq2 = (const float*)d_in[12]; const float* bq2 = (const float*)d_in[13];
  const float* Wk2 = (const float*)d_in[14]; const float* bk2 = (const float*)d_in[15];
  const float* Wv2 = (const float*)d_in[16]; const float* bv2 = (const float*)d_in[17];
  const float* We2 = (const float*)d_in[18];
  const float* Ws2 = (const float*)d_in[19]; const float* bs2 = (const float*)d_in[20];
  const float* Wc  = (const float*)d_in[21]; const float* bc  = (const float*)d_in[22];
  float* out = (float*)d_out;

  const int* srcI = ei;        // edge_index[0]
  const int* dstI = ei + NE;   // edge_index[1]

  // ---- workspace layout (256B-aligned slices) ----
  char* ws = (char*)d_ws;
  size_t off = 0;
  auto alloc = [&](size_t bytes) {
    void* p = ws + off;
    off += (bytes + 255) & ~(size_t)255;
    return p;
  };
  float* Q1   = (float*)alloc((size_t)NN * H1 * 4);
  float* S1   = (float*)alloc((size_t)NN * H1 * 4);
  u16*   KV1  = (u16*)alloc((size_t)NN * 2 * H1 * 2); // [N][k|v] bf16
  float* Q2   = (float*)alloc((size_t)NN * H2 * 4);
  float* S2   = (float*)alloc((size_t)NN * H2 * 4);
  u16*   KV2  = (u16*)alloc((size_t)NN * 2 * H2 * 2);
  float* QE1  = (float*)alloc((size_t)NN * DE * 4);   // We1 @ q per node
  float* QE2  = (float*)alloc((size_t)NN * DE * 4);
  float* EA1  = (float*)alloc((size_t)NN * DE * 4);   // softmax-weighted edge_attr
  float* EA2  = (float*)alloc((size_t)NN * DE * 4);
  float* Hp1  = (float*)alloc((size_t)NN * H1 * 4);   // partial h (pre-relu)
  float* Hp2  = (float*)alloc((size_t)NN * H2 * 4);
  float* h1   = (float*)alloc((size_t)NN * H1 * 4);
  float* h2   = (float*)alloc((size_t)NN * H2 * 4);
  u16*   EAc  = (u16*)alloc((size_t)NE * DE * 2);     // bf16 edge_attr, CSR order
  u16* B1h = (u16*)alloc((size_t)4 * H1 * DIN * 2);
  u16* B1l = (u16*)alloc((size_t)4 * H1 * DIN * 2);
  u16* B2h = (u16*)alloc((size_t)4 * H2 * H1 * 2);
  u16* B2l = (u16*)alloc((size_t)4 * H2 * H1 * 2);
  u16* W1eh = (u16*)alloc((size_t)DE * H1 * 2);       // We1 straight split [64][128]
  u16* W1el = (u16*)alloc((size_t)DE * H1 * 2);
  u16* W2eh = (u16*)alloc((size_t)DE * H2 * 2);       // We2 straight split [64][64]
  u16* W2el = (u16*)alloc((size_t)DE * H2 * 2);
  u16* T1h = (u16*)alloc((size_t)H1 * DE * 2);        // We1^T split [128][64]
  u16* T1l = (u16*)alloc((size_t)H1 * DE * 2);
  u16* T2h = (u16*)alloc((size_t)H2 * DE * 2);        // We2^T split [64][64]
  u16* T2l = (u16*)alloc((size_t)H2 * DE * 2);
  float* b1cat = (float*)alloc(4 * H1 * 4);
  float* b2cat = (float*)alloc(4 * H2 * 4);
  int* deg       = (int*)alloc(NN * 4);
  int* cursor    = (int*)alloc(NN * 4);
  int* row_start = (int*)alloc((NN + 1) * 4);
  int* part      = (int*)alloc(((NN + 255) / 256) * 256 * 4);
  int* chunkSums = (int*)alloc(256 * 4);
  int* eid       = (int*)alloc(NE * 4);
  int* src_csr   = (int*)alloc(NE * 4);
  (void)ws_size; (void)in_sizes; (void)n_in; (void)out_size;

  const int nchunks = (NN + 255) / 256;  // 196 (<= 256)

  // ---- pack weights ----
  packwt_kernel<<<256, 256, 0, stream>>>(Wq1, Wk1, Wv1, Ws1, bq1, bk1, bv1, bs1,
                                         B1h, B1l, b1cat, DIN, H1, 4);
  packwt_kernel<<<128, 256, 0, stream>>>(Wq2, Wk2, Wv2, Ws2, bq2, bk2, bv2, bs2,
                                         B2h, B2l, b2cat, H1, H2, 4);
  // We straight splits (for QE = Q @ We^T: Bt[d][k] = We[d][k])
  splitcopy_kernel<<<(DE * H1 + 255) / 256, 256, 0, stream>>>(We1, W1eh, W1el,
                                                              DE * H1);
  splitcopy_kernel<<<(DE * H2 + 255) / 256, 256, 0, stream>>>(We2, W2eh, W2el,
                                                              DE * H2);
  // We transposed splits (for h += EA @ We: Bt[c][d] = We[d][c])
  packwt_kernel<<<64, 256, 0, stream>>>(We1, nullptr, nullptr, nullptr, nullptr,
                                        nullptr, nullptr, nullptr, T1h, T1l,
                                        nullptr, DE, H1, 1);
  packwt_kernel<<<32, 256, 0, stream>>>(We2, nullptr, nullptr, nullptr, nullptr,
                                        nullptr, nullptr, nullptr, T2h, T2l,
                                        nullptr, DE, H2, 1);

  // ---- CSR build (sort edges by dst; deterministic within-node order) ----
  hipMemsetAsync(deg, 0, NN * sizeof(int), stream);
  hipMemsetAsync(cursor, 0, NN * sizeof(int), stream);
  hist_kernel<<<(NE + 255) / 256, 256, 0, stream>>>(dstI, deg, NE);
  scan1_kernel<<<nchunks, 256, 0, stream>>>(deg, part, chunkSums, NN);
  scan2_kernel<<<1, 256, 0, stream>>>(chunkSums, nchunks);
  scan3_kernel<<<nchunks, 256, 0, stream>>>(deg, part, chunkSums, row_start, NN, NE);
  scatter_kernel<<<(NE + 255) / 256, 256, 0, stream>>>(dstI, row_start, cursor,
                                                       eid, NE);
  sort_extract_kernel<<<(NN + 255) / 256, 256, 0, stream>>>(eid, row_start, srcI,
                                                            src_csr, NN);
  // gather edge_attr to CSR order as bf16 (random read happens ONCE)
  ea_gather_kernel<<<(NE + 7) / 8, 256, 0, stream>>>(edge_attr, eid, EAc, NE);

  const int MB = (NN + 127) / 128;  // 391 row blocks

  // ================= Layer 1 (C = H1 = 128) =================
  mfma_gemm_kernel<128, 2><<<dim3(4 * H1 / 128, MB), 256, 0, stream>>>(
      x, nullptr, B1h, B1l, b1cat, nullptr, Q1, KV1, S1, nullptr, NN, 4 * H1,
      DIN, H1);
  mfma_gemm_kernel<64, 0><<<dim3(1, MB), 256, 0, stream>>>(
      Q1, nullptr, W1eh, W1el, nullptr, QE1, nullptr, nullptr, nullptr, nullptr,
      NN, DE, H1, 0);
  fused_edge_kernel<H1><<<(NN + 3) / 4, 256, 0, stream>>>(
      Q1, QE1, S1, KV1, EAc, row_start, src_csr, Hp1, EA1,
      0.08838834764831845f, NN);
  mfma_gemm_kernel<128, 3><<<dim3(1, MB), 256, 0, stream>>>(
      EA1, nullptr, T1h, T1l, nullptr, h1, nullptr, nullptr, nullptr, Hp1, NN,
      H1, DE, 0);

  // ================= Layer 2 (C = H2 = 64) =================
  mfma_gemm_kernel<64, 2><<<dim3(4 * H2 / 64, MB), 256, 0, stream>>>(
      h1, nullptr, B2h, B2l, b2cat, nullptr, Q2, KV2, S2, nullptr, NN, 4 * H2,
      H1, H2);
  mfma_gemm_kernel<64, 0><<<dim3(1, MB), 256, 0, stream>>>(
      Q2, nullptr, W2eh, W2el, nullptr, QE2, nullptr, nullptr, nullptr, nullptr,
      NN, DE, H2, 0);
  fused_edge_kernel<H2><<<(NN + 3) / 4, 256, 0, stream>>>(
      Q2, QE2, S2, KV2, EAc, row_start, src_csr, Hp2, EA2, 0.125f, NN);
  mfma_gemm_kernel<64, 3><<<dim3(1, MB), 256, 0, stream>>>(
      EA2, nullptr, T2h, T2l, nullptr, h2, nullptr, nullptr, nullptr, Hp2, NN,
      H2, DE, 0);

  // ================= Classifier =================
  classifier_kernel<<<(NN + 3) / 4, 256, 0, stream>>>(h2, Wc, bc, out, NN);
}

// Round 18
// 485.556 us; speedup vs baseline: 1.1039x; 1.1039x over previous
//
#include <hip/hip_runtime.h>
#include <math.h>

// Problem constants (match reference setup_inputs)
constexpr int NN  = 50000;   // nodes
constexpr int NE  = 640000;  // edges
constexpr int DIN = 256;
constexpr int DE  = 64;
constexpr int H1  = 128;
constexpr int H2  = 64;
constexpr int EWS = H1 + H2; // 192: combined edge-emb row stride

using u16 = unsigned short;
typedef __attribute__((ext_vector_type(8))) short bf16x8;
typedef __attribute__((ext_vector_type(4))) float f32x4;
typedef __attribute__((ext_vector_type(4))) unsigned int u32x4;  // clang vector: ok for nontemporal builtins

// ---- fp32 -> bf16 (RTN) and back ----
__device__ inline u16 f2bf(float f) {
  unsigned u = __float_as_uint(f);
  unsigned r = (u + 0x7FFFu + ((u >> 16) & 1u)) >> 16;
  return (u16)r;
}
__device__ inline float bf2f(u16 h) { return __uint_as_float(((unsigned)h) << 16); }
__device__ inline unsigned pack2(u16 a, u16 b) {
  return (unsigned)a | ((unsigned)b << 16);
}
__device__ inline f32x4 mfma16(bf16x8 a, bf16x8 b, f32x4 c) {
  return __builtin_amdgcn_mfma_f32_16x16x32_bf16(a, b, c, 0, 0, 0);
}

// ---- pack nmats weight matrices W[K,C] into transposed split Bt[n][k] (n = which*C+cc)
__global__ __launch_bounds__(256) void packwt_kernel(
    const float* __restrict__ W0, const float* __restrict__ W1,
    const float* __restrict__ W2, const float* __restrict__ W3,
    const float* __restrict__ b0, const float* __restrict__ b1,
    const float* __restrict__ b2, const float* __restrict__ b3,
    u16* __restrict__ Bth, u16* __restrict__ Btl, float* __restrict__ bcat,
    int K, int C, int nmats) {
  int total = nmats * C * K;
  for (int idx = blockIdx.x * blockDim.x + threadIdx.x; idx < total;
       idx += gridDim.x * blockDim.x) {
    int k = idx % K;
    int n = idx / K;             // n = which*C + cc
    int which = n / C, cc = n % C;
    const float* W = which == 0 ? W0 : which == 1 ? W1 : which == 2 ? W2 : W3;
    float v = W[k * C + cc];
    u16 h = f2bf(v);
    Bth[(size_t)n * K + k] = h;
    if (Btl) Btl[(size_t)n * K + k] = f2bf(v - bf2f(h));
    if (k == 0 && bcat) {
      const float* b = which == 0 ? b0 : which == 1 ? b1 : which == 2 ? b2 : b3;
      bcat[n] = b ? b[cc] : 0.f;
    }
  }
}

// ---- CSR build ----
__global__ __launch_bounds__(256) void hist_kernel(const int* __restrict__ dst,
                                                   int* __restrict__ deg, int nE) {
  int e = blockIdx.x * blockDim.x + threadIdx.x;
  if (e < nE) atomicAdd(&deg[dst[e]], 1);
}

__global__ __launch_bounds__(256) void scan1_kernel(const int* __restrict__ deg,
                                                    int* __restrict__ part,
                                                    int* __restrict__ chunkSums,
                                                    int n) {
  __shared__ int s[256];
  int tid = threadIdx.x;
  int i = blockIdx.x * 256 + tid;
  int v0 = (i < n) ? deg[i] : 0;
  s[tid] = v0;
  __syncthreads();
  for (int off = 1; off < 256; off <<= 1) {
    int v = (tid >= off) ? s[tid - off] : 0;
    __syncthreads();
    s[tid] += v;
    __syncthreads();
  }
  if (i < n) part[i] = s[tid];
  if (tid == 255) chunkSums[blockIdx.x] = s[255];
}

__global__ __launch_bounds__(256) void scan2_kernel(int* __restrict__ chunkSums,
                                                    int nchunks) {
  __shared__ int s[256];
  int tid = threadIdx.x;
  s[tid] = (tid < nchunks) ? chunkSums[tid] : 0;
  __syncthreads();
  for (int off = 1; off < 256; off <<= 1) {
    int v = (tid >= off) ? s[tid - off] : 0;
    __syncthreads();
    s[tid] += v;
    __syncthreads();
  }
  if (tid < nchunks) chunkSums[tid] = s[tid];
}

__global__ __launch_bounds__(256) void scan3_kernel(const int* __restrict__ deg,
                                                    const int* __restrict__ part,
                                                    const int* __restrict__ chunkSums,
                                                    int* __restrict__ row_start,
                                                    int n, int nE) {
  int i = blockIdx.x * 256 + threadIdx.x;
  if (i < n)
    row_start[i] = part[i] - deg[i] + (blockIdx.x ? chunkSums[blockIdx.x - 1] : 0);
  if (i == 0) row_start[n] = nE;
}

__global__ __launch_bounds__(256) void scatter_kernel(const int* __restrict__ dst,
                                                      const int* __restrict__ row_start,
                                                      int* __restrict__ cursor,
                                                      int* __restrict__ eid, int nE) {
  int e = blockIdx.x * blockDim.x + threadIdx.x;
  if (e >= nE) return;
  int d = dst[e];
  int pos = row_start[d] + atomicAdd(&cursor[d], 1);
  eid[pos] = e;
}

__global__ __launch_bounds__(256) void sort_extract_kernel(
    int* __restrict__ eid, const int* __restrict__ row_start,
    const int* __restrict__ srcI, int* __restrict__ src_csr, int n) {
  int v = blockIdx.x * blockDim.x + threadIdx.x;
  if (v >= n) return;
  int b = row_start[v], e = row_start[v + 1];
  for (int i = b + 1; i < e; i++) {
    int key = eid[i];
    int j = i - 1;
    while (j >= b && eid[j] > key) { eid[j + 1] = eid[j]; j--; }
    eid[j + 1] = key;
  }
  for (int i = b; i < e; i++) src_csr[i] = srcI[eid[i]];
}

// ---- split-bf16 MFMA GEMM (generic, BM=128, 256 thr):
// out[M,Nn] = A[M,K](f32) @ Bt^T + bias
// EPI=0: fp32 -> Cout (stride Nn)
// EPI=2: projection split: cols [0,Cl)->Qp f32, [Cl,3Cl)->KVp bf16 [M][2Cl], [3Cl,4Cl)->Sp f32
//        (requires BN <= Cl so each block hits exactly one segment)
template <int BN, int EPI>
__global__ __launch_bounds__(256) void mfma_gemm_kernel(
    const float* __restrict__ A, const int* __restrict__ ridx,
    const u16* __restrict__ Bth, const u16* __restrict__ Btl,
    const float* __restrict__ bias, float* __restrict__ Cout,
    float* __restrict__ Qp, u16* __restrict__ KVp, float* __restrict__ Sp,
    int M, int Nn, int K, int Cl) {
  constexpr int BM = 128, BK = 32;
  constexpr int NI = BN / 32;  // 16-col frags per wave (wave covers BN/2)
  constexpr int SM_STAGE = (BM + BN) * BK * 2;
  constexpr int SM_EPI = (EPI >= 1) ? BM * BN : 0;
  constexpr int SM = SM_STAGE > SM_EPI ? SM_STAGE : SM_EPI;
  __shared__ __align__(16) u16 smem[SM];
  u16* Ah = smem;
  u16* Al = smem + BM * BK;
  u16* Bh = smem + 2 * BM * BK;
  u16* Bl = smem + 2 * BM * BK + BN * BK;
  int tid = threadIdx.x;
  int lane = tid & 63, wid = tid >> 6;
  int wm = wid >> 1, wn = wid & 1;
  int row0 = blockIdx.y * BM, col0 = blockIdx.x * BN;
  int k8 = lane >> 4, rb = lane & 15;

  f32x4 acc[4][NI];
#pragma unroll
  for (int mi = 0; mi < 4; mi++)
#pragma unroll
    for (int ni = 0; ni < NI; ni++) acc[mi][ni] = (f32x4){0.f, 0.f, 0.f, 0.f};

  // A staging assignments: 2 chunks (8 f32 each) per thread
  size_t aoff[2];
  int sdst[2];
  for (int p = 0; p < 2; p++) {
    int idx = p * 256 + tid;
    int r = idx >> 2, c = idx & 3;
    int ar = row0 + r;
    if (ar >= M) ar = M - 1;
    if (ridx) ar = ridx[ar];
    aoff[p] = (size_t)ar * K + c * 8;
    sdst[p] = r * BK + ((c ^ ((r >> 1) & 3)) << 3);  // chunk-XOR swizzle
  }

  for (int k0 = 0; k0 < K; k0 += BK) {
    __syncthreads();
    // stage A: read f32, split to bf16 hi/lo
#pragma unroll
    for (int p = 0; p < 2; p++) {
      const float* s = A + aoff[p] + k0;
      float4 u = *(const float4*)s, v = *(const float4*)(s + 4);
      float f[8] = {u.x, u.y, u.z, u.w, v.x, v.y, v.z, v.w};
      u16 h[8], l[8];
#pragma unroll
      for (int j = 0; j < 8; j++) {
        h[j] = f2bf(f[j]);
        l[j] = f2bf(f[j] - bf2f(h[j]));
      }
      *(uint4*)&Ah[sdst[p]] = make_uint4(pack2(h[0], h[1]), pack2(h[2], h[3]),
                                         pack2(h[4], h[5]), pack2(h[6], h[7]));
      *(uint4*)&Al[sdst[p]] = make_uint4(pack2(l[0], l[1]), pack2(l[2], l[3]),
                                         pack2(l[4], l[5]), pack2(l[6], l[7]));
    }
    // stage B (already bf16 split, [Nn][K] row-major)
#pragma unroll
    for (int p = 0; p < (BN * 4) / 256; p++) {
      int idx = p * 256 + tid;
      int n = idx >> 2, c = idx & 3;
      size_t goff = (size_t)(col0 + n) * K + k0 + c * 8;
      int doff = n * BK + ((c ^ ((n >> 1) & 3)) << 3);
      *(uint4*)&Bh[doff] = *(const uint4*)&Bth[goff];
      *(uint4*)&Bl[doff] = *(const uint4*)&Btl[goff];
    }
    __syncthreads();
    // fragments
    bf16x8 ah[4], al[4], bh[NI], bl[NI];
#pragma unroll
    for (int mi = 0; mi < 4; mi++) {
      int row = wm * 64 + mi * 16 + rb;
      int off = row * BK + ((k8 ^ ((row >> 1) & 3)) << 3);
      ah[mi] = *(const bf16x8*)&Ah[off];
      al[mi] = *(const bf16x8*)&Al[off];
    }
#pragma unroll
    for (int ni = 0; ni < NI; ni++) {
      int cn = wn * (BN / 2) + ni * 16 + rb;
      int off = cn * BK + ((k8 ^ ((cn >> 1) & 3)) << 3);
      bh[ni] = *(const bf16x8*)&Bh[off];
      bl[ni] = *(const bf16x8*)&Bl[off];
    }
#pragma unroll
    for (int mi = 0; mi < 4; mi++)
#pragma unroll
      for (int ni = 0; ni < NI; ni++) {
        f32x4 c = acc[mi][ni];
        c = mfma16(ah[mi], bh[ni], c);
        c = mfma16(al[mi], bh[ni], c);
        c = mfma16(ah[mi], bl[ni], c);
        acc[mi][ni] = c;
      }
  }

  // epilogue: D layout col=lane&15, row=(lane>>4)*4+reg (m89-verified)
  bool kvseg = false;
  if constexpr (EPI == 2) {
    int seg = col0 / Cl;
    kvseg = (seg == 1 || seg == 2);
    if (!kvseg) {
      float* dst = (seg == 0) ? Qp : Sp;
      int cbase = (seg == 0) ? col0 : col0 - 3 * Cl;
#pragma unroll
      for (int ni = 0; ni < NI; ni++) {
        int cfrag = wn * (BN / 2) + ni * 16 + rb;
        float bv = bias ? bias[col0 + cfrag] : 0.f;
#pragma unroll
        for (int mi = 0; mi < 4; mi++) {
#pragma unroll
          for (int q = 0; q < 4; q++) {
            int row = row0 + wm * 64 + mi * 16 + k8 * 4 + q;
            if (row < M)
              dst[(size_t)row * Cl + cbase + cfrag] = acc[mi][ni][q] + bv;
          }
        }
      }
      return;
    }
  }
  if (kvseg) {
    // stage bf16 tile in LDS (XOR-swizzled), then coalesced dwordx4 writes
    __syncthreads();
    u16* S = smem;  // [BM][BN] u16
#pragma unroll
    for (int ni = 0; ni < NI; ni++) {
      int coll = wn * (BN / 2) + ni * 16 + rb;
      float bv = bias ? bias[col0 + coll] : 0.f;
#pragma unroll
      for (int mi = 0; mi < 4; mi++) {
#pragma unroll
        for (int q = 0; q < 4; q++) {
          int rowl = wm * 64 + mi * 16 + k8 * 4 + q;
          S[rowl * BN + (coll ^ (((rowl >> 2) & 3) << 4))] =
              f2bf(acc[mi][ni][q] + bv);
        }
      }
    }
    __syncthreads();
    u16* dbase = KVp;
    size_t dstride = 2 * Cl;
    int dcol0 = col0 - Cl;
    constexpr int PASSES = (BM * BN * 2) / (256 * 16);
#pragma unroll
    for (int p = 0; p < PASSES; p++) {
      int idx = p * 256 + tid;      // uint4 index
      int r = idx / (BN / 8);
      int cp = idx % (BN / 8);
      int row = row0 + r;
      int cps = cp ^ (((r >> 2) & 3) << 1);  // inverse of the <<4 u16 swizzle
      if (row < M)
        *(uint4*)&dbase[(size_t)row * dstride + dcol0 + cp * 8] =
            *(const uint4*)&S[r * BN + cps * 8];
    }
    return;
  }
  if constexpr (EPI == 0) {
#pragma unroll
    for (int ni = 0; ni < NI; ni++) {
      int col = col0 + wn * (BN / 2) + ni * 16 + rb;
      float bv = bias ? bias[col] : 0.f;
#pragma unroll
      for (int mi = 0; mi < 4; mi++) {
#pragma unroll
        for (int q = 0; q < 4; q++) {
          int row = row0 + wm * 64 + mi * 16 + k8 * 4 + q;
          if (row < M) Cout[(size_t)row * Nn + col] = acc[mi][ni][q] + bv;
        }
      }
    }
  }
}

// ---- dedicated edge-embedding GEMM: EwB[NE][192] bf16 = edge_attr @ Ec^T
// ORIGINAL edge order, streaming. BM=128, 512 thr (wave = 32-row strip).
// Direct-A: lane loads A-frag from global (no A-LDS, no K-loop barriers).
// Pure bf16 (A-hi x B-hi only): output stored bf16, extra split precision is
// below storage rounding. B ([192][64], 24 KB) staged once, swizzle c^=(n&7).
__global__ __launch_bounds__(512, 4) void edge_gemm_kernel(
    const float* __restrict__ A, const u16* __restrict__ Bth,
    u16* __restrict__ Cbf) {
  constexpr int BM = 128, BN = 192, K = DE;  // K = 64
  constexpr int NI = 6;  // wave covers 96 cols
  __shared__ __align__(16) u16 smem[BN * K];  // 24576 B
  u16* BhL = smem;
  int tid = threadIdx.x;
  int lane = tid & 63, wid = tid >> 6;
  int wm = wid >> 1, wn = wid & 1;   // wm: 4 strips of 32 rows; wn: 2 col-halves
  int row0 = blockIdx.x * BM;
  int k8 = lane >> 4, rb = lane & 15;

  // stage B once: 1536 uint4 tasks / 512 thr = 3 per thread
#pragma unroll
  for (int p = 0; p < 3; p++) {
    int m = p * 512 + tid;
    int n = m >> 3, c = m & 7;
    *(uint4*)&BhL[n * K + ((c ^ (n & 7)) << 3)] =
        *(const uint4*)&Bth[n * K + c * 8];
  }
  __syncthreads();

  f32x4 acc[2][NI];
#pragma unroll
  for (int mi = 0; mi < 2; mi++)
#pragma unroll
    for (int ni = 0; ni < NI; ni++) acc[mi][ni] = (f32x4){0.f, 0.f, 0.f, 0.f};

  // K-loop: no barriers. A-frag loaded directly from global per lane.
#pragma unroll
  for (int k0 = 0; k0 < K; k0 += 32) {
#pragma unroll
    for (int mi = 0; mi < 2; mi++) {
      int row = row0 + wm * 32 + mi * 16 + rb;
      const float* s = A + (size_t)row * K + k0 + k8 * 8;
      float4 u = *(const float4*)s, v = *(const float4*)(s + 4);
      uint4 pk = make_uint4(pack2(f2bf(u.x), f2bf(u.y)), pack2(f2bf(u.z), f2bf(u.w)),
                            pack2(f2bf(v.x), f2bf(v.y)), pack2(f2bf(v.z), f2bf(v.w)));
      bf16x8 ah = *(bf16x8*)&pk;
      int chunk = (k0 >> 3) + k8;
#pragma unroll
      for (int ni = 0; ni < NI; ni++) {
        int cn = wn * 96 + ni * 16 + rb;
        int off = cn * K + ((chunk ^ (cn & 7)) << 3);
        acc[mi][ni] = mfma16(ah, *(const bf16x8*)&BhL[off], acc[mi][ni]);
      }
    }
  }

  // epilogue: two 64-row halves through reused LDS (S = 64*192 u16 = 24576 B)
  u16* S = smem;
#pragma unroll
  for (int half = 0; half < 2; half++) {
    __syncthreads();
    if ((wm >> 1) == half) {
#pragma unroll
      for (int ni = 0; ni < NI; ni++) {
        int coll = wn * 96 + ni * 16 + rb;
#pragma unroll
        for (int mi = 0; mi < 2; mi++) {
#pragma unroll
          for (int q = 0; q < 4; q++) {
            int rowl = (wm & 1) * 32 + mi * 16 + k8 * 4 + q;
            S[rowl * BN + (coll ^ (((rowl >> 2) & 3) << 4))] =
                f2bf(acc[mi][ni][q]);
          }
        }
      }
    }
    __syncthreads();
    // 64 rows x 24 uint4 = 1536 / 512 thr = 3 passes; nontemporal stores
#pragma unroll
    for (int p = 0; p < 3; p++) {
      int idx = p * 512 + tid;
      int r = idx / (BN / 8);
      int cp = idx % (BN / 8);
      int row = row0 + half * 64 + r;
      int cps = cp ^ (((r >> 2) & 3) << 1);
      __builtin_nontemporal_store(*(const u32x4*)&S[r * BN + cps * 8],
                                  (u32x4*)&Cbf[(size_t)row * BN + cp * 8]);
    }
  }
}

// ---- fused edge pass: 8-edge-batched online softmax + message agg + skip + relu
// Ew indexed via eid (original edge order); gathers batched for MLP.
template <int C, int EOFF>
__global__ __launch_bounds__(256) void fused_edge_kernel(
    const float* __restrict__ Q, const float* __restrict__ SKIP,
    const u16* __restrict__ KV, const u16* __restrict__ Ew,
    const int* __restrict__ row_start, const int* __restrict__ src_csr,
    const int* __restrict__ eid, float* __restrict__ h, float scale, int n) {
  constexpr int CPL = C / 64;  // channels per lane
  constexpr int EB = 8;        // edges per batch
  int node = blockIdx.x * 4 + (threadIdx.x >> 6);
  int lane = threadIdx.x & 63;
  if (node >= n) return;
  int ch = lane * CPL;
  float q[CPL], acc[CPL], skip[CPL];
#pragma unroll
  for (int j = 0; j < CPL; j++) {
    q[j] = Q[(size_t)node * C + ch + j];
    skip[j] = SKIP[(size_t)node * C + ch + j];
    acc[j] = 0.f;
  }
  float m = -INFINITY, denom = 0.f;
  int b = row_start[node], e = row_start[node + 1];
  for (int i = b; i < e; i += EB) {
    float part[EB], vv[EB][CPL];
#pragma unroll
    for (int u = 0; u < EB; u++) {
      int idx = (i + u < e) ? i + u : e - 1;  // tail: clamp loads, zeroed by w=0
      int s = src_csr[idx];
      int eo = eid[idx];
      const u16* kvp = KV + (size_t)s * (2 * C);
      const u16* Ee = Ew + (size_t)eo * EWS + EOFF;
      float kk[CPL], ev[CPL];
      if constexpr (CPL == 2) {
        unsigned uk = *(const unsigned*)(kvp + ch);
        unsigned uv = *(const unsigned*)(kvp + C + ch);
        unsigned ue = *(const unsigned*)(Ee + ch);
        kk[0] = bf2f((u16)uk); kk[1] = bf2f((u16)(uk >> 16));
        vv[u][0] = bf2f((u16)uv); vv[u][1] = bf2f((u16)(uv >> 16));
        ev[0] = bf2f((u16)ue); ev[1] = bf2f((u16)(ue >> 16));
      } else {
        kk[0] = bf2f(kvp[ch]);
        vv[u][0] = bf2f(kvp[C + ch]);
        ev[0] = bf2f(Ee[ch]);
      }
      float p = 0.f;
#pragma unroll
      for (int j = 0; j < CPL; j++) {
        p = fmaf(q[j], kk[j] + ev[j], p);
        vv[u][j] += ev[j];
      }
      part[u] = p;
    }
    // EB independent butterfly reductions (ILP across trees)
#pragma unroll
    for (int off = 32; off > 0; off >>= 1) {
#pragma unroll
      for (int u = 0; u < EB; u++) part[u] += __shfl_xor(part[u], off);
    }
    float l[EB];
#pragma unroll
    for (int u = 0; u < EB; u++)
      l[u] = (i + u < e) ? part[u] * scale : -INFINITY;
    float bm = l[0];
#pragma unroll
    for (int u = 1; u < EB; u++) bm = fmaxf(bm, l[u]);
    float nm = fmaxf(bm, m);
    float f = expf(m - nm);  // 0 on first batch (m = -inf)
    float w[EB];
#pragma unroll
    for (int u = 0; u < EB; u++) w[u] = expf(l[u] - nm);  // -inf -> 0
    float wsum = 0.f;
#pragma unroll
    for (int u = 0; u < EB; u++) wsum += w[u];
    denom = denom * f + wsum;
#pragma unroll
    for (int j = 0; j < CPL; j++) {
      float a = acc[j] * f;
#pragma unroll
      for (int u = 0; u < EB; u++) a = fmaf(w[u], vv[u][j], a);
      acc[j] = a;
    }
    m = nm;
  }
  float inv = 1.f / (denom + 1e-16f);
#pragma unroll
  for (int j = 0; j < CPL; j++)
    h[(size_t)node * C + ch + j] = fmaxf(acc[j] * inv + skip[j], 0.f);
}

// ---- out[n] = h2[n] @ Wc + bc  (wave per node) ----
__global__ __launch_bounds__(256) void classifier_kernel(
    const float* __restrict__ h2, const float* __restrict__ Wc,
    const float* __restrict__ bc, float* __restrict__ out, int n) {
  int w = blockIdx.x * 4 + (threadIdx.x >> 6);
  int lane = threadIdx.x & 63;
  if (w >= n) return;
  float v = h2[(size_t)w * 64 + lane] * Wc[lane];
#pragma unroll
  for (int off = 32; off > 0; off >>= 1) v += __shfl_xor(v, off);
  if (lane == 0) out[w] = v + bc[0];
}

extern "C" void kernel_launch(void* const* d_in, const int* in_sizes, int n_in,
                              void* d_out, int out_size, void* d_ws,
                              size_t ws_size, hipStream_t stream) {
  const float* x         = (const float*)d_in[0];
  const int*   ei        = (const int*)d_in[1];
  const float* edge_attr = (const float*)d_in[2];
  const float* Wq1 = (const float*)d_in[3];  const float* bq1 = (const float*)d_in[4];
  const float* Wk1 = (const float*)d_in[5];  const float* bk1 = (const float*)d_in[6];
  const float* Wv1 = (const float*)d_in[7];  const float* bv1 = (const float*)d_in[8];
  const float* We1 = (const float*)d_in[9];
  const float* Ws1 = (const float*)d_in[10]; const float* bs1 = (const float*)d_in[11];
  const float* Wq2 = (const float*)d_in[12]; const float* bq2 = (const float*)d_in[13];
  const float* Wk2 = (const float*)d_in[14]; const float* bk2 = (const float*)d_in[15];
  const float* Wv2 = (const float*)d_in[16]; const float* bv2 = (const float*)d_in[17];
  const float* We2 = (const float*)d_in[18];
  const float* Ws2 = (const float*)d_in[19]; const float* bs2 = (const float*)d_in[20];
  const float* Wc  = (const float*)d_in[21]; const float* bc  = (const float*)d_in[22];
  float* out = (float*)d_out;

  const int* srcI = ei;        // edge_index[0]
  const int* dstI = ei + NE;   // edge_index[1]

  // ---- workspace layout (256B-aligned slices) ----
  char* ws = (char*)d_ws;
  size_t off = 0;
  auto alloc = [&](size_t bytes) {
    void* p = ws + off;
    off += (bytes + 255) & ~(size_t)255;
    return p;
  };
  u16*   EwB  = (u16*)alloc((size_t)NE * EWS * 2);    // combined bf16 edge emb [E][192], ORIGINAL order
  float* Q1   = (float*)alloc((size_t)NN * H1 * 4);
  float* S1   = (float*)alloc((size_t)NN * H1 * 4);
  u16*   KV1  = (u16*)alloc((size_t)NN * 2 * H1 * 2); // [N][k|v] bf16
  float* Q2   = (float*)alloc((size_t)NN * H2 * 4);
  float* S2   = (float*)alloc((size_t)NN * H2 * 4);
  u16*   KV2  = (u16*)alloc((size_t)NN * 2 * H2 * 2);
  float* h1   = (float*)alloc((size_t)NN * H1 * 4);
  float* h2   = (float*)alloc((size_t)NN * H2 * 4);
  u16* B1h = (u16*)alloc((size_t)4 * H1 * DIN * 2);
  u16* B1l = (u16*)alloc((size_t)4 * H1 * DIN * 2);
  u16* B2h = (u16*)alloc((size_t)4 * H2 * H1 * 2);
  u16* B2l = (u16*)alloc((size_t)4 * H2 * H1 * 2);
  u16* Ech = (u16*)alloc((size_t)EWS * DE * 2);       // [192][64] = [We1|We2]^T
  float* b1cat = (float*)alloc(4 * H1 * 4);
  float* b2cat = (float*)alloc(4 * H2 * 4);
  int* deg       = (int*)alloc(NN * 4);
  int* cursor    = (int*)alloc(NN * 4);
  int* row_start = (int*)alloc((NN + 1) * 4);
  int* part      = (int*)alloc(((NN + 255) / 256) * 256 * 4);
  int* chunkSums = (int*)alloc(256 * 4);
  int* eid       = (int*)alloc(NE * 4);
  int* src_csr   = (int*)alloc(NE * 4);
  (void)ws_size; (void)in_sizes; (void)n_in; (void)out_size;

  const int nchunks = (NN + 255) / 256;  // 196 (<= 256)

  // ---- pack weights (transpose + bf16 split) ----
  packwt_kernel<<<256, 256, 0, stream>>>(Wq1, Wk1, Wv1, Ws1, bq1, bk1, bv1, bs1,
                                         B1h, B1l, b1cat, DIN, H1, 4);
  packwt_kernel<<<128, 256, 0, stream>>>(Wq2, Wk2, Wv2, Ws2, bq2, bk2, bv2, bs2,
                                         B2h, B2l, b2cat, H1, H2, 4);
  packwt_kernel<<<64, 256, 0, stream>>>(We1, nullptr, nullptr, nullptr, nullptr,
                                        nullptr, nullptr, nullptr, Ech, nullptr,
                                        nullptr, DE, H1, 1);
  packwt_kernel<<<32, 256, 0, stream>>>(We2, nullptr, nullptr, nullptr, nullptr,
                                        nullptr, nullptr, nullptr,
                                        Ech + (size_t)H1 * DE, nullptr,
                                        nullptr, DE, H2, 1);

  // ---- CSR build (sort edges by dst; deterministic within-node order) ----
  hipMemsetAsync(deg, 0, NN * sizeof(int), stream);
  hipMemsetAsync(cursor, 0, NN * sizeof(int), stream);
  hist_kernel<<<(NE + 255) / 256, 256, 0, stream>>>(dstI, deg, NE);
  scan1_kernel<<<nchunks, 256, 0, stream>>>(deg, part, chunkSums, NN);
  scan2_kernel<<<1, 256, 0, stream>>>(chunkSums, nchunks);
  scan3_kernel<<<nchunks, 256, 0, stream>>>(deg, part, chunkSums, row_start, NN, NE);
  scatter_kernel<<<(NE + 255) / 256, 256, 0, stream>>>(dstI, row_start, cursor,
                                                       eid, NE);
  sort_extract_kernel<<<(NN + 255) / 256, 256, 0, stream>>>(eid, row_start, srcI,
                                                            src_csr, NN);

  // ---- edge-embedding GEMM (both layers, bf16 out, ORIGINAL edge order) ----
  edge_gemm_kernel<<<NE / 128, 512, 0, stream>>>(edge_attr, Ech, EwB);

  // ================= Layer 1 (C = H1 = 128) =================
  mfma_gemm_kernel<128, 2><<<dim3(4 * H1 / 128, (NN + 127) / 128), 256, 0, stream>>>(
      x, nullptr, B1h, B1l, b1cat, nullptr, Q1, KV1, S1, NN, 4 * H1, DIN, H1);
  fused_edge_kernel<H1, 0><<<(NN + 3) / 4, 256, 0, stream>>>(
      Q1, S1, KV1, EwB, row_start, src_csr, eid, h1, 0.08838834764831845f, NN);

  // ================= Layer 2 (C = H2 = 64) =================
  mfma_gemm_kernel<64, 2><<<dim3(4 * H2 / 64, (NN + 127) / 128), 256, 0, stream>>>(
      h1, nullptr, B2h, B2l, b2cat, nullptr, Q2, KV2, S2, NN, 4 * H2, H1, H2);
  fused_edge_kernel<H2, H1><<<(NN + 3) / 4, 256, 0, stream>>>(
      Q2, S2, KV2, EwB, row_start, src_csr, eid, h2, 0.125f, NN);

  // ================= Classifier =================
  classifier_kernel<<<(NN + 3) / 4, 256, 0, stream>>>(h2, Wc, bc, out, NN);
}